// Round 4
// baseline (2291.958 us; speedup 1.0000x reference)
//
#include <hip/hip_runtime.h>
#include <hip/hip_bf16.h>

typedef unsigned short u16t;
typedef unsigned int   u32t;

#define NNODE 100000
#define DIN   256
#define HIDN  128
#define DOUTN 64
#define NNZE  1600000
#define EDIR  500000
#define EBI   1000000

__device__ __forceinline__ u16t f2bf(float f){
  u32t u = __float_as_uint(f);
  u += 0x7FFFu + ((u>>16)&1u);          // round-to-nearest-even
  return (u16t)(u>>16);
}
__device__ __forceinline__ float2 up2(u32t w){
  return make_float2(__uint_as_float(w<<16), __uint_as_float(w&0xFFFF0000u));
}
__device__ __forceinline__ void unpack8(uint4 w, float* f){
  f[0]=__uint_as_float(w.x<<16); f[1]=__uint_as_float(w.x&0xFFFF0000u);
  f[2]=__uint_as_float(w.y<<16); f[3]=__uint_as_float(w.y&0xFFFF0000u);
  f[4]=__uint_as_float(w.z<<16); f[5]=__uint_as_float(w.z&0xFFFF0000u);
  f[6]=__uint_as_float(w.w<<16); f[7]=__uint_as_float(w.w&0xFFFF0000u);
}

// ---------------- GEMM1: xw[N][128] = X[N][256] @ W_gcn[256][128], f32 in, bf16 out ----------------
__global__ __launch_bounds__(256) void gemm1_kernel(const float* __restrict__ X,
                                                    const float* __restrict__ Wg,
                                                    u16t* __restrict__ xwb){
  __shared__ __align__(16) float Xs[16][256];     // 16 KB
  __shared__ __align__(16) u16t  Wt[128*128];     // 32 KB: [col h][kk], granules swizzled by (h&15)
  const int t = threadIdx.x;
  const int row0 = blockIdx.x * 16;
  for(int i=t;i<16*64;i+=256){                    // float4-vectorized X stage
    int r=i>>6, c4=i&63;
    *(float4*)&Xs[r][c4*4] = *(const float4*)&X[(size_t)(row0+r)*DIN + c4*4];
  }
  const int cx = t & 63;
  const int ry = t >> 6;
  float acc[4][2];
  #pragma unroll
  for(int j=0;j<4;j++){ acc[j][0]=0.f; acc[j][1]=0.f; }
  #pragma unroll 1
  for(int kc=0;kc<2;kc++){
    const int k0 = kc*128;
    __syncthreads();
    for(int i=t;i<128*128;i+=256){
      int h = i & 127, kk = i >> 7;
      Wt[h*128 + (((kk>>3)^(h&15))<<3) + (kk&7)] = f2bf(Wg[(size_t)(k0+kk)*HIDN + h]);
    }
    __syncthreads();
    #pragma unroll
    for(int g=0;g<16;g++){
      uint4 w0 = *(const uint4*)&Wt[ cx     *128 + ((g^(cx&15))<<3)];
      uint4 w1 = *(const uint4*)&Wt[(cx+64) *128 + ((g^(cx&15))<<3)];
      float w0f[8], w1f[8];
      unpack8(w0,w0f); unpack8(w1,w1f);
      #pragma unroll
      for(int j=0;j<4;j++){
        const float* xp = &Xs[ry*4+j][k0 + g*8];
        float xr[8];
        *(float4*)&xr[0] = *(const float4*)xp;
        *(float4*)&xr[4] = *(const float4*)(xp+4);
        #pragma unroll
        for(int m=0;m<8;m++){
          acc[j][0] += xr[m]*w0f[m];
          acc[j][1] += xr[m]*w1f[m];
        }
      }
    }
  }
  #pragma unroll
  for(int j=0;j<4;j++){
    size_t gr = (size_t)(row0 + ry*4 + j);
    xwb[gr*HIDN + cx]      = f2bf(acc[j][0]);
    xwb[gr*HIDN + cx + 64] = f2bf(acc[j][1]);
  }
}

// ---------------- scatter: hidden[dst] += v * xw[src] ----------------
__global__ __launch_bounds__(256) void scatter_kernel(const u16t* __restrict__ xwb,
                                                      const float* __restrict__ gv,
                                                      const int*  __restrict__ gi,
                                                      float* __restrict__ hidden){
  int e = blockIdx.x*4 + (threadIdx.x>>6);
  int l = threadIdx.x & 63;
  int dst = gi[e], src = gi[NNZE+e];
  float v = gv[e];
  u32t w = ((const u32t*)(xwb + (size_t)src*HIDN))[l];
  float2 x = up2(w);
  float* hr = hidden + (size_t)dst*HIDN;
  atomicAdd(&hr[2*l],   v*x.x);
  atomicAdd(&hr[2*l+1], v*x.y);
}

// ---------------- GEMM2: in-place hidden[N][128] f32 -> per-row packed [SRC bf16 x128 | DST bf16 x128] ----------------
// interleaved within SRC/DST: [2c]=miu col c, [2c+1]=sigma col c
__global__ __launch_bounds__(256) void gemm2_kernel(float* __restrict__ hidden,
                                                    const float* __restrict__ Wm,
                                                    const float* __restrict__ Wsg){
  __shared__ __align__(16) float Hs[16][128];    // 8 KB
  __shared__ __align__(16) u16t  Wt[256*64];     // 32 KB: [col cp][kk], granules swizzled by (cp&7)
  const int t = threadIdx.x;
  const int row0 = blockIdx.x * 16;
  for(int i=t;i<16*32;i+=256){
    int r=i>>5, c4=i&31;
    *(float4*)&Hs[r][c4*4] = *(const float4*)&hidden[(size_t)(row0+r)*HIDN + c4*4];
  }
  const int cx = t & 127;
  const int ry = t >> 7;
  float acc[8][2];
  #pragma unroll
  for(int j=0;j<8;j++){ acc[j][0]=0.f; acc[j][1]=0.f; }
  #pragma unroll 1
  for(int kc=0;kc<2;kc++){
    const int k0 = kc*64;
    __syncthreads();
    for(int i=t;i<256*64;i+=256){
      int cp = i & 255, kk = i >> 8;
      int k  = k0 + kk;
      int half = cp >> 7;            // 0 -> SRC (W rows 0..127), 1 -> DST (rows 128..255)
      int ci   = cp & 127;
      const float* Wsrc = (ci & 1) ? Wsg : Wm;
      u16t w = f2bf(Wsrc[(size_t)(half*128 + k)*DOUTN + (ci>>1)]);
      Wt[cp*64 + (((kk>>3)^(cp&7))<<3) + (kk&7)] = w;
    }
    __syncthreads();
    #pragma unroll
    for(int g=0;g<8;g++){
      uint4 w0 = *(const uint4*)&Wt[ cx      *64 + ((g^(cx&7))<<3)];
      uint4 w1 = *(const uint4*)&Wt[(cx+128) *64 + ((g^(cx&7))<<3)];
      float w0f[8], w1f[8];
      unpack8(w0,w0f); unpack8(w1,w1f);
      #pragma unroll
      for(int j=0;j<8;j++){
        const float* xp = &Hs[ry*8+j][k0 + g*8];
        float xr[8];
        *(float4*)&xr[0] = *(const float4*)xp;
        *(float4*)&xr[4] = *(const float4*)(xp+4);
        #pragma unroll
        for(int m=0;m<8;m++){
          acc[j][0] += xr[m]*w0f[m];
          acc[j][1] += xr[m]*w1f[m];
        }
      }
    }
  }
  // in-place write: row n's 512B of f32 hidden becomes [SRC bf16 x128][DST bf16 x128]
  __syncthreads();                     // all Hs reads done (paranoia; Hs is LDS, but cheap)
  u16t* Bu = (u16t*)hidden;
  #pragma unroll
  for(int j=0;j<8;j++){
    size_t n = (size_t)(row0 + ry*8 + j);
    Bu[n*256 + cx]       = f2bf(acc[j][0]);   // SRC part
    Bu[n*256 + 128 + cx] = f2bf(acc[j][1]);   // DST part
  }
}

// ---------------- directed-edge heads (f32 out) ----------------
__global__ __launch_bounds__(256) void edge_kernel(const u16t* __restrict__ Bu,
                                                   const int*  __restrict__ ed,
                                                   const float* __restrict__ nin,
                                                   const float* __restrict__ nout,
                                                   float* __restrict__ ein,
                                                   float* __restrict__ eout){
  int e = blockIdx.x*4 + (threadIdx.x>>6);
  int l = threadIdx.x & 63;
  int s = ed[e], d = ed[EDIR+e];
  const u32t* rs = (const u32t*)(Bu + (size_t)s*256);
  const u32t* rd = (const u32t*)(Bu + (size_t)d*256);
  float2 Ss = up2(rs[l]);        // SRC[s]
  float2 Ds = up2(rs[64+l]);     // DST[s]
  float2 Sd = up2(rd[l]);        // SRC[d]
  float2 Dd = up2(rd[64+l]);     // DST[d]
  size_t o = (size_t)e*DOUTN + l;
  float miu_in  = Ss.x + Dd.x, ls_in  = Ss.y + Dd.y;
  float miu_out = Sd.x + Ds.x, ls_out = Sd.y + Ds.y;
  ein[o]  = nin[o]  * __expf(ls_in)  + miu_in;
  eout[o] = nout[o] * __expf(ls_out) + miu_out;
}

// ---------------- bi-edge heads + node accumulation ----------------
__global__ __launch_bounds__(256) void bi_kernel(const u16t* __restrict__ Bu,
                                                 const int*  __restrict__ be,
                                                 const float* __restrict__ bv,
                                                 float* __restrict__ nmiu,
                                                 float* __restrict__ nvar){
  int e = blockIdx.x*4 + (threadIdx.x>>6);
  int l = threadIdx.x & 63;
  int b0 = be[e], b1 = be[EBI+e];
  float v = bv[e];
  float2 S = up2(((const u32t*)(Bu + (size_t)b0*256))[l]);       // SRC[b0]
  float2 D = up2(((const u32t*)(Bu + (size_t)b1*256))[64+l]);    // DST[b1]
  atomicAdd(&nmiu[(size_t)b0*DOUTN + l], v*(S.x+D.x));
  atomicAdd(&nvar[(size_t)b0*DOUTN + l], v*v*__expf(S.y+D.y));
}

// ---------------- finalize node embedding (in-place on nmiu==out) ----------------
__global__ __launch_bounds__(256) void finalize_kernel(float* __restrict__ nmiu,
                                                       const float* __restrict__ nvar,
                                                       const float* __restrict__ nn){
  int i = blockIdx.x*256 + threadIdx.x;
  // exp(0.5*log(v)) == sqrt(v); v==0 -> 0 matches reference (exp(-inf)=0)
  nmiu[i] = nn[i] * sqrtf(nvar[i]) + nmiu[i];
}

extern "C" void kernel_launch(void* const* d_in, const int* in_sizes, int n_in,
                              void* d_out, int out_size, void* d_ws, size_t ws_size,
                              hipStream_t stream){
  const float* X    = (const float*)d_in[0];
  const float* Wg   = (const float*)d_in[1];
  const float* Wm   = (const float*)d_in[2];
  const float* Wsg  = (const float*)d_in[3];
  const float* gv   = (const float*)d_in[4];
  const float* bv   = (const float*)d_in[5];
  const float* nin  = (const float*)d_in[6];
  const float* nout = (const float*)d_in[7];
  const float* nnod = (const float*)d_in[8];
  const int*  gi   = (const int*)d_in[9];
  const int*  ed   = (const int*)d_in[10];
  const int*  be   = (const int*)d_in[11];

  // workspace layout, 76.8 MB total:
  //  A [0, 25.6 MB):      xw bf16 (N x 128)            -> reused as node_var f32 (N x 64)
  //  B [25.6, 76.8 MB):   hidden f32 (N x 128)         -> in-place per-row [SRC|DST] bf16 after gemm2
  u16t*  xwb    = (u16t*)d_ws;
  float* nvar   = (float*)d_ws;
  float* hidden = (float*)((char*)d_ws + 25600000);
  u16t*  Bu     = (u16t*)hidden;

  float* out  = (float*)d_out;          // node_embed region doubles as nmiu accumulator
  float* ein  = out + (size_t)NNODE*DOUTN;
  float* eout = ein + (size_t)EDIR*DOUTN;

  hipMemsetAsync(hidden, 0, (size_t)NNODE*HIDN*sizeof(float), stream);
  hipMemsetAsync(out,    0, (size_t)NNODE*DOUTN*sizeof(float), stream);   // nmiu = 0
  gemm1_kernel   <<<NNODE/16, 256, 0, stream>>>(X, Wg, xwb);
  scatter_kernel <<<NNZE/4,  256, 0, stream>>>(xwb, gv, gi, hidden);
  gemm2_kernel   <<<NNODE/16, 256, 0, stream>>>(hidden, Wm, Wsg);
  hipMemsetAsync(nvar, 0, (size_t)NNODE*DOUTN*sizeof(float), stream);     // nvar = 0 (xw dead)
  edge_kernel    <<<EDIR/4,  256, 0, stream>>>(Bu, ed, nin, nout, ein, eout);
  bi_kernel      <<<EBI/4,   256, 0, stream>>>(Bu, be, bv, out, nvar);
  finalize_kernel<<<NNODE*DOUTN/256, 256, 0, stream>>>(out, nvar, nnod);
}

// Round 5
// 1496.094 us; speedup vs baseline: 1.5320x; 1.5320x over previous
//
#include <hip/hip_runtime.h>

typedef unsigned short u16t;
typedef unsigned int   u32t;

#define NNODE 100000
#define DIN   256
#define HIDN  128
#define DOUTN 64
#define NNZE  1600000
#define EDIR  500000
#define EBI   1000000

__device__ __forceinline__ u16t f2bf(float f){
  u32t u = __float_as_uint(f);
  u += 0x7FFFu + ((u>>16)&1u);          // round-to-nearest-even
  return (u16t)(u>>16);
}
__device__ __forceinline__ float2 up2(u32t w){
  return make_float2(__uint_as_float(w<<16), __uint_as_float(w&0xFFFF0000u));
}
__device__ __forceinline__ void unpack8(uint4 w, float* f){
  f[0]=__uint_as_float(w.x<<16); f[1]=__uint_as_float(w.x&0xFFFF0000u);
  f[2]=__uint_as_float(w.y<<16); f[3]=__uint_as_float(w.y&0xFFFF0000u);
  f[4]=__uint_as_float(w.z<<16); f[5]=__uint_as_float(w.z&0xFFFF0000u);
  f[6]=__uint_as_float(w.w<<16); f[7]=__uint_as_float(w.w&0xFFFF0000u);
}

// ---------------- histogram: cnt[key]++ ----------------
__global__ __launch_bounds__(256) void hist_kernel(const int* __restrict__ keys, int E,
                                                   u32t* __restrict__ cnt){
  int e = blockIdx.x*256 + threadIdx.x;
  if(e < E) atomicAdd(&cnt[keys[e]], 1u);
}

// ---------------- single-block exclusive scan over NNODE bins ----------------
// in: cur[] holds counts; out: offs[0..NNODE] = exclusive scan, cur[] = scan (cursor init)
__global__ __launch_bounds__(1024) void scan_kernel(u32t* __restrict__ cur,
                                                    u32t* __restrict__ offs){
  __shared__ u32t part[1024];
  const int t = threadIdx.x;
  const int CH = 98;                       // 1024*98 = 100352 >= NNODE
  const int base = t*CH;
  u32t s = 0;
  for(int i=0;i<CH;i++){ int idx=base+i; if(idx<NNODE) s += cur[idx]; }
  part[t] = s; __syncthreads();
  for(int off=1; off<1024; off<<=1){
    u32t v = (t>=off) ? part[t-off] : 0u;
    __syncthreads();
    part[t] += v;
    __syncthreads();
  }
  u32t run = (t==0) ? 0u : part[t-1];
  for(int i=0;i<CH;i++){
    int idx=base+i;
    if(idx<NNODE){
      u32t c = cur[idx];
      offs[idx] = run; cur[idx] = run;
      run += c;
    }
  }
  if(t==1023) offs[NNODE] = run;
}

// ---------------- bucket fill: bucket[cur[key]++] = (payload, value) ----------------
__global__ __launch_bounds__(256) void bucket_kernel(const int* __restrict__ keys,
                                                     const int* __restrict__ pay,
                                                     const float* __restrict__ val,
                                                     int E,
                                                     u32t* __restrict__ cur,
                                                     uint2* __restrict__ bucket){
  int e = blockIdx.x*256 + threadIdx.x;
  if(e < E){
    u32t pos = atomicAdd(&cur[keys[e]], 1u);
    bucket[pos] = make_uint2((u32t)pay[e], __float_as_uint(val[e]));
  }
}

// ---------------- GEMM1: xw[N][128] = X[N][256] @ W_gcn[256][128], f32 in, bf16 out ----------------
__global__ __launch_bounds__(256) void gemm1_kernel(const float* __restrict__ X,
                                                    const float* __restrict__ Wg,
                                                    u16t* __restrict__ xwb){
  __shared__ __align__(16) float Xs[16][256];     // 16 KB
  __shared__ __align__(16) u16t  Wt[128*128];     // 32 KB: [col h][kk], granules swizzled by (h&15)
  const int t = threadIdx.x;
  const int row0 = blockIdx.x * 16;
  for(int i=t;i<16*64;i+=256){
    int r=i>>6, c4=i&63;
    *(float4*)&Xs[r][c4*4] = *(const float4*)&X[(size_t)(row0+r)*DIN + c4*4];
  }
  const int cx = t & 63;
  const int ry = t >> 6;
  float acc[4][2];
  #pragma unroll
  for(int j=0;j<4;j++){ acc[j][0]=0.f; acc[j][1]=0.f; }
  #pragma unroll 1
  for(int kc=0;kc<2;kc++){
    const int k0 = kc*128;
    __syncthreads();
    for(int i=t;i<128*128;i+=256){
      int h = i & 127, kk = i >> 7;
      Wt[h*128 + (((kk>>3)^(h&15))<<3) + (kk&7)] = f2bf(Wg[(size_t)(k0+kk)*HIDN + h]);
    }
    __syncthreads();
    #pragma unroll
    for(int g=0;g<16;g++){
      uint4 w0 = *(const uint4*)&Wt[ cx     *128 + ((g^(cx&15))<<3)];
      uint4 w1 = *(const uint4*)&Wt[(cx+64) *128 + ((g^(cx&15))<<3)];
      float w0f[8], w1f[8];
      unpack8(w0,w0f); unpack8(w1,w1f);
      #pragma unroll
      for(int j=0;j<4;j++){
        const float* xp = &Xs[ry*4+j][k0 + g*8];
        float xr[8];
        *(float4*)&xr[0] = *(const float4*)xp;
        *(float4*)&xr[4] = *(const float4*)(xp+4);
        #pragma unroll
        for(int m=0;m<8;m++){
          acc[j][0] += xr[m]*w0f[m];
          acc[j][1] += xr[m]*w1f[m];
        }
      }
    }
  }
  #pragma unroll
  for(int j=0;j<4;j++){
    size_t gr = (size_t)(row0 + ry*4 + j);
    xwb[gr*HIDN + cx]      = f2bf(acc[j][0]);
    xwb[gr*HIDN + cx + 64] = f2bf(acc[j][1]);
  }
}

// ---------------- GCN gather-reduce: hidden[n] = sum over bucket[n] of v * xw[src] ----------------
// one wave per node; lane l owns cols (2l, 2l+1); output bf16 packed u32 words
__global__ __launch_bounds__(256) void gcn_gather_kernel(const u16t* __restrict__ xwb,
                                                         const uint2* __restrict__ bucket,
                                                         const u32t* __restrict__ offs,
                                                         u32t* __restrict__ hiddenw){
  int n = blockIdx.x*4 + (threadIdx.x>>6);
  if(n >= NNODE) return;
  int l = threadIdx.x & 63;
  u32t start = offs[n], end = offs[n+1];
  const u32t* xww = (const u32t*)xwb;
  float acc0 = 0.f, acc1 = 0.f;
  for(u32t b = start; b < end; b += 64){
    int nb = min(64, (int)(end - b));
    uint2 ent = make_uint2(0u, 0u);
    if(l < nb) ent = bucket[b + l];
    for(int j=0;j<nb;j++){
      u32t s  = __shfl(ent.x, j);
      float v = __uint_as_float(__shfl((int)ent.y, j));
      float2 x = up2(xww[(size_t)s*64 + l]);
      acc0 += v*x.x;
      acc1 += v*x.y;
    }
  }
  hiddenw[(size_t)n*64 + l] = (u32t)f2bf(acc0) | ((u32t)f2bf(acc1)<<16);
}

// ---------------- GEMM2: hidden bf16 [N][128] @ Wcat -> Bu per-row [SRC bf16 x128 | DST bf16 x128] ----------------
// interleaved within SRC/DST: [2c]=miu col c, [2c+1]=sigma col c
__global__ __launch_bounds__(256) void gemm2_kernel(const u32t* __restrict__ hiddenw,
                                                    const float* __restrict__ Wm,
                                                    const float* __restrict__ Wsg,
                                                    u16t* __restrict__ Bu){
  __shared__ __align__(16) float Hs[16][128];    // 8 KB
  __shared__ __align__(16) u16t  Wt[256*64];     // 32 KB
  const int t = threadIdx.x;
  const int row0 = blockIdx.x * 16;
  for(int i=t;i<16*64;i+=256){
    int r=i>>6, w=i&63;
    float2 f = up2(hiddenw[(size_t)(row0+r)*64 + w]);
    Hs[r][2*w]   = f.x;
    Hs[r][2*w+1] = f.y;
  }
  const int cx = t & 127;
  const int ry = t >> 7;
  float acc[8][2];
  #pragma unroll
  for(int j=0;j<8;j++){ acc[j][0]=0.f; acc[j][1]=0.f; }
  #pragma unroll 1
  for(int kc=0;kc<2;kc++){
    const int k0 = kc*64;
    __syncthreads();
    for(int i=t;i<256*64;i+=256){
      int cp = i & 255, kk = i >> 8;
      int k  = k0 + kk;
      int half = cp >> 7;
      int ci   = cp & 127;
      const float* Wsrc = (ci & 1) ? Wsg : Wm;
      Wt[cp*64 + (((kk>>3)^(cp&7))<<3) + (kk&7)] = f2bf(Wsrc[(size_t)(half*128 + k)*DOUTN + (ci>>1)]);
    }
    __syncthreads();
    #pragma unroll
    for(int g=0;g<8;g++){
      uint4 w0 = *(const uint4*)&Wt[ cx      *64 + ((g^(cx&7))<<3)];
      uint4 w1 = *(const uint4*)&Wt[(cx+128) *64 + ((g^(cx&7))<<3)];
      float w0f[8], w1f[8];
      unpack8(w0,w0f); unpack8(w1,w1f);
      #pragma unroll
      for(int j=0;j<8;j++){
        const float* xp = &Hs[ry*8+j][k0 + g*8];
        float xr[8];
        *(float4*)&xr[0] = *(const float4*)xp;
        *(float4*)&xr[4] = *(const float4*)(xp+4);
        #pragma unroll
        for(int m=0;m<8;m++){
          acc[j][0] += xr[m]*w0f[m];
          acc[j][1] += xr[m]*w1f[m];
        }
      }
    }
  }
  #pragma unroll
  for(int j=0;j<8;j++){
    size_t n = (size_t)(row0 + ry*8 + j);
    Bu[n*256 + cx]       = f2bf(acc[j][0]);   // SRC half
    Bu[n*256 + 128 + cx] = f2bf(acc[j][1]);   // DST half
  }
}

// ---------------- directed-edge heads (f32 out) ----------------
__global__ __launch_bounds__(256) void edge_kernel(const u16t* __restrict__ Bu,
                                                   const int*  __restrict__ ed,
                                                   const float* __restrict__ nin,
                                                   const float* __restrict__ nout,
                                                   float* __restrict__ ein,
                                                   float* __restrict__ eout){
  int e = blockIdx.x*4 + (threadIdx.x>>6);
  int l = threadIdx.x & 63;
  int s = ed[e], d = ed[EDIR+e];
  const u32t* rs = (const u32t*)(Bu + (size_t)s*256);
  const u32t* rd = (const u32t*)(Bu + (size_t)d*256);
  float2 Ss = up2(rs[l]);        // SRC[s]
  float2 Ds = up2(rs[64+l]);     // DST[s]
  float2 Sd = up2(rd[l]);        // SRC[d]
  float2 Dd = up2(rd[64+l]);     // DST[d]
  size_t o = (size_t)e*DOUTN + l;
  float miu_in  = Ss.x + Dd.x, ls_in  = Ss.y + Dd.y;
  float miu_out = Sd.x + Ds.x, ls_out = Sd.y + Ds.y;
  ein[o]  = nin[o]  * __expf(ls_in)  + miu_in;
  eout[o] = nout[o] * __expf(ls_out) + miu_out;
}

// ---------------- bi gather-reduce + finalize (fused, no atomics) ----------------
// one wave per node n; lane l owns output col l
__global__ __launch_bounds__(256) void bi_gather_kernel(const u16t* __restrict__ Bu,
                                                        const uint2* __restrict__ bucket,
                                                        const u32t* __restrict__ offs,
                                                        const float* __restrict__ nn,
                                                        float* __restrict__ out){
  int n = blockIdx.x*4 + (threadIdx.x>>6);
  if(n >= NNODE) return;
  int l = threadIdx.x & 63;
  const u32t* Bw = (const u32t*)Bu;
  float2 S = up2(Bw[(size_t)n*128 + l]);           // SRC[n] (miu_l, sigma_l)
  u32t start = offs[n], end = offs[n+1];
  float nmiu = 0.f, nvar = 0.f;
  for(u32t b = start; b < end; b += 64){
    int nb = min(64, (int)(end - b));
    uint2 ent = make_uint2(0u, 0u);
    if(l < nb) ent = bucket[b + l];
    for(int j=0;j<nb;j++){
      u32t b1 = __shfl(ent.x, j);
      float v = __uint_as_float(__shfl((int)ent.y, j));
      float2 D = up2(Bw[(size_t)b1*128 + 64 + l]); // DST[b1]
      nmiu += v*(S.x + D.x);
      nvar += v*v*__expf(S.y + D.y);
    }
  }
  size_t o = (size_t)n*DOUTN + l;
  // exp(0.5*log(v)) == sqrt(v); v==0 -> 0 matches reference
  out[o] = nn[o]*sqrtf(nvar) + nmiu;
}

extern "C" void kernel_launch(void* const* d_in, const int* in_sizes, int n_in,
                              void* d_out, int out_size, void* d_ws, size_t ws_size,
                              hipStream_t stream){
  const float* X    = (const float*)d_in[0];
  const float* Wg   = (const float*)d_in[1];
  const float* Wm   = (const float*)d_in[2];
  const float* Wsg  = (const float*)d_in[3];
  const float* gv   = (const float*)d_in[4];
  const float* bv   = (const float*)d_in[5];
  const float* nin  = (const float*)d_in[6];
  const float* nout = (const float*)d_in[7];
  const float* nnod = (const float*)d_in[8];
  const int*  gi   = (const int*)d_in[9];
  const int*  ed   = (const int*)d_in[10];
  const int*  be   = (const int*)d_in[11];

  // workspace (76.8 MB, same footprint as passing round 4):
  // region A [0, 51.2 MB):
  //   early:  gcn bucket uint2 @0 (12.8MB) | gcn offs @12.8M (400,004B) | gcn cur @13.2M+8 (400,000B)
  //           xwb bf16 @25.6M (25.6MB)
  //   late:   Bu (N x 512B) — overwrites all of A after gcn phase is dead
  // region B [51.2, 76.8 MB):
  //   early:  hidden bf16-packed u32 words (25.6MB)
  //   late:   bi bucket uint2 @51.2M (8MB) | bi offs @59.2M | bi cur @59.6M+8
  char* ws = (char*)d_ws;
  uint2* gbuck   = (uint2*)ws;
  u32t*  goffs   = (u32t*)(ws + 12800000);
  u32t*  gcur    = (u32t*)(ws + 13200008);
  u16t*  xwb     = (u16t*)(ws + 25600000);
  u32t*  hiddenw = (u32t*)(ws + 51200000);
  u16t*  Bu      = (u16t*)ws;
  uint2* bbuck   = (uint2*)(ws + 51200000);
  u32t*  boffs   = (u32t*)(ws + 59200000);
  u32t*  bcur    = (u32t*)(ws + 59600008);

  float* out  = (float*)d_out;
  float* ein  = out + (size_t)NNODE*DOUTN;
  float* eout = ein + (size_t)EDIR*DOUTN;

  // --- GCN aggregation via counting-sort + gather-reduce ---
  hipMemsetAsync(gcur, 0, NNODE*sizeof(u32t), stream);
  hist_kernel      <<<NNZE/256,    256,  0, stream>>>(gi, NNZE, gcur);
  scan_kernel      <<<1,           1024, 0, stream>>>(gcur, goffs);
  bucket_kernel    <<<NNZE/256,    256,  0, stream>>>(gi, gi+NNZE, gv, NNZE, gcur, gbuck);
  gemm1_kernel     <<<NNODE/16,    256,  0, stream>>>(X, Wg, xwb);
  gcn_gather_kernel<<<NNODE/4,     256,  0, stream>>>(xwb, gbuck, goffs, hiddenw);
  gemm2_kernel     <<<NNODE/16,    256,  0, stream>>>(hiddenw, Wm, Wsg, Bu);
  // --- BI bucketing (region B free now) ---
  hipMemsetAsync(bcur, 0, NNODE*sizeof(u32t), stream);
  hist_kernel      <<<(EBI+255)/256, 256,  0, stream>>>(be, EBI, bcur);
  scan_kernel      <<<1,            1024, 0, stream>>>(bcur, boffs);
  bucket_kernel    <<<(EBI+255)/256, 256,  0, stream>>>(be, be+EBI, bv, EBI, bcur, bbuck);
  // --- heads ---
  edge_kernel      <<<EDIR/4,      256,  0, stream>>>(Bu, ed, nin, nout, ein, eout);
  bi_gather_kernel <<<NNODE/4,     256,  0, stream>>>(Bu, bbuck, boffs, nnod, out);
}

// Round 6
// 993.961 us; speedup vs baseline: 2.3059x; 1.5052x over previous
//
#include <hip/hip_runtime.h>

typedef unsigned short u16t;
typedef unsigned int   u32t;

#define NNODE 100000
#define DIN   256
#define HIDN  128
#define DOUTN 64
#define NNZE  1600000
#define EDIR  500000
#define EBI   1000000
#define NBLKS 391            // ceil(NNODE/256)

__device__ __forceinline__ u16t f2bf(float f){
  u32t u = __float_as_uint(f);
  u += 0x7FFFu + ((u>>16)&1u);          // round-to-nearest-even
  return (u16t)(u>>16);
}
__device__ __forceinline__ float2 up2(u32t w){
  return make_float2(__uint_as_float(w<<16), __uint_as_float(w&0xFFFF0000u));
}
__device__ __forceinline__ void unpack8(uint4 w, float* f){
  f[0]=__uint_as_float(w.x<<16); f[1]=__uint_as_float(w.x&0xFFFF0000u);
  f[2]=__uint_as_float(w.y<<16); f[3]=__uint_as_float(w.y&0xFFFF0000u);
  f[4]=__uint_as_float(w.z<<16); f[5]=__uint_as_float(w.z&0xFFFF0000u);
  f[6]=__uint_as_float(w.w<<16); f[7]=__uint_as_float(w.w&0xFFFF0000u);
}

// ---------------- histogram: cnt[key]++ ----------------
__global__ __launch_bounds__(256) void hist_kernel(const int* __restrict__ keys, int E,
                                                   u32t* __restrict__ cnt){
  int e = blockIdx.x*256 + threadIdx.x;
  if(e < E) atomicAdd(&cnt[keys[e]], 1u);
}

// ---------------- hierarchical scan, phase A: per-block local exclusive scan ----------------
__global__ __launch_bounds__(256) void scanA_kernel(const u32t* __restrict__ cnt,
                                                    u32t* __restrict__ offs,
                                                    u32t* __restrict__ partials){
  __shared__ u32t sh[256];
  int t = threadIdx.x, idx = blockIdx.x*256 + t;
  u32t v = (idx < NNODE) ? cnt[idx] : 0u;
  sh[t] = v; __syncthreads();
  #pragma unroll
  for(int off=1; off<256; off<<=1){
    u32t x = (t>=off) ? sh[t-off] : 0u;
    __syncthreads();
    sh[t] += x;
    __syncthreads();
  }
  if(idx < NNODE) offs[idx] = sh[t] - v;          // local exclusive
  if(t == 255) partials[blockIdx.x] = sh[255];    // block total
}

// ---------------- phase B: scan the block totals (single small block) ----------------
__global__ __launch_bounds__(512) void scanB_kernel(u32t* __restrict__ partials){
  __shared__ u32t sh[512];
  int t = threadIdx.x;
  u32t v = (t < NBLKS) ? partials[t] : 0u;
  sh[t] = v; __syncthreads();
  #pragma unroll
  for(int off=1; off<512; off<<=1){
    u32t x = (t>=off) ? sh[t-off] : 0u;
    __syncthreads();
    sh[t] += x;
    __syncthreads();
  }
  if(t < NBLKS) partials[t] = sh[t] - v;          // exclusive block offsets
  if(t == 511) partials[NBLKS] = sh[511];         // grand total
}

// ---------------- phase C: add block offsets, init cursors ----------------
__global__ __launch_bounds__(256) void scanC_kernel(u32t* __restrict__ offs,
                                                    u32t* __restrict__ cur,
                                                    const u32t* __restrict__ partials){
  int idx = blockIdx.x*256 + threadIdx.x;
  if(idx < NNODE){
    u32t o = offs[idx] + partials[blockIdx.x];
    offs[idx] = o; cur[idx] = o;
  }
  if(idx == 0) offs[NNODE] = partials[NBLKS];
}

// ---------------- bucket fill: bucket[cur[key]++] = (payload, value) ----------------
__global__ __launch_bounds__(256) void bucket_kernel(const int* __restrict__ keys,
                                                     const int* __restrict__ pay,
                                                     const float* __restrict__ val,
                                                     int E,
                                                     u32t* __restrict__ cur,
                                                     uint2* __restrict__ bucket){
  int e = blockIdx.x*256 + threadIdx.x;
  if(e < E){
    u32t pos = atomicAdd(&cur[keys[e]], 1u);
    bucket[pos] = make_uint2((u32t)pay[e], __float_as_uint(val[e]));
  }
}

// ---------------- GEMM1: xw[N][128] = X[N][256] @ W_gcn[256][128], f32 in, bf16 out ----------------
__global__ __launch_bounds__(256) void gemm1_kernel(const float* __restrict__ X,
                                                    const float* __restrict__ Wg,
                                                    u16t* __restrict__ xwb){
  __shared__ __align__(16) float Xs[16][256];     // 16 KB
  __shared__ __align__(16) u16t  Wt[128*128];     // 32 KB
  const int t = threadIdx.x;
  const int row0 = blockIdx.x * 16;
  for(int i=t;i<16*64;i+=256){
    int r=i>>6, c4=i&63;
    *(float4*)&Xs[r][c4*4] = *(const float4*)&X[(size_t)(row0+r)*DIN + c4*4];
  }
  const int cx = t & 63;
  const int ry = t >> 6;
  float acc[4][2];
  #pragma unroll
  for(int j=0;j<4;j++){ acc[j][0]=0.f; acc[j][1]=0.f; }
  #pragma unroll 1
  for(int kc=0;kc<2;kc++){
    const int k0 = kc*128;
    __syncthreads();
    for(int i=t;i<128*128;i+=256){
      int h = i & 127, kk = i >> 7;
      Wt[h*128 + (((kk>>3)^(h&15))<<3) + (kk&7)] = f2bf(Wg[(size_t)(k0+kk)*HIDN + h]);
    }
    __syncthreads();
    #pragma unroll
    for(int g=0;g<16;g++){
      uint4 w0 = *(const uint4*)&Wt[ cx     *128 + ((g^(cx&15))<<3)];
      uint4 w1 = *(const uint4*)&Wt[(cx+64) *128 + ((g^(cx&15))<<3)];
      float w0f[8], w1f[8];
      unpack8(w0,w0f); unpack8(w1,w1f);
      #pragma unroll
      for(int j=0;j<4;j++){
        const float* xp = &Xs[ry*4+j][k0 + g*8];
        float xr[8];
        *(float4*)&xr[0] = *(const float4*)xp;
        *(float4*)&xr[4] = *(const float4*)(xp+4);
        #pragma unroll
        for(int m=0;m<8;m++){
          acc[j][0] += xr[m]*w0f[m];
          acc[j][1] += xr[m]*w1f[m];
        }
      }
    }
  }
  #pragma unroll
  for(int j=0;j<4;j++){
    size_t gr = (size_t)(row0 + ry*4 + j);
    xwb[gr*HIDN + cx]      = f2bf(acc[j][0]);
    xwb[gr*HIDN + cx + 64] = f2bf(acc[j][1]);
  }
}

// ---------------- GCN gather-reduce: hidden[n] = sum over bucket[n] of v * xw[src] ----------------
__global__ __launch_bounds__(256) void gcn_gather_kernel(const u16t* __restrict__ xwb,
                                                         const uint2* __restrict__ bucket,
                                                         const u32t* __restrict__ offs,
                                                         u32t* __restrict__ hiddenw){
  int n = blockIdx.x*4 + (threadIdx.x>>6);
  if(n >= NNODE) return;
  int l = threadIdx.x & 63;
  u32t start = offs[n], end = offs[n+1];
  const u32t* xww = (const u32t*)xwb;
  float acc0 = 0.f, acc1 = 0.f;
  for(u32t b = start; b < end; b += 64){
    int nb = min(64, (int)(end - b));
    uint2 ent = make_uint2(0u, 0u);
    if(l < nb) ent = bucket[b + l];
    for(int j=0;j<nb;j++){
      u32t s  = __shfl(ent.x, j);
      float v = __uint_as_float(__shfl((int)ent.y, j));
      float2 x = up2(xww[(size_t)s*64 + l]);
      acc0 += v*x.x;
      acc1 += v*x.y;
    }
  }
  hiddenw[(size_t)n*64 + l] = (u32t)f2bf(acc0) | ((u32t)f2bf(acc1)<<16);
}

// ---------------- GEMM2: hidden bf16 [N][128] @ Wcat -> Bu per-row [SRC bf16 x128 | DST bf16 x128] ----------------
__global__ __launch_bounds__(256) void gemm2_kernel(const u32t* __restrict__ hiddenw,
                                                    const float* __restrict__ Wm,
                                                    const float* __restrict__ Wsg,
                                                    u16t* __restrict__ Bu){
  __shared__ __align__(16) float Hs[16][128];    // 8 KB
  __shared__ __align__(16) u16t  Wt[256*64];     // 32 KB
  const int t = threadIdx.x;
  const int row0 = blockIdx.x * 16;
  for(int i=t;i<16*64;i+=256){
    int r=i>>6, w=i&63;
    float2 f = up2(hiddenw[(size_t)(row0+r)*64 + w]);
    Hs[r][2*w]   = f.x;
    Hs[r][2*w+1] = f.y;
  }
  const int cx = t & 127;
  const int ry = t >> 7;
  float acc[8][2];
  #pragma unroll
  for(int j=0;j<8;j++){ acc[j][0]=0.f; acc[j][1]=0.f; }
  #pragma unroll 1
  for(int kc=0;kc<2;kc++){
    const int k0 = kc*64;
    __syncthreads();
    for(int i=t;i<256*64;i+=256){
      int cp = i & 255, kk = i >> 8;
      int k  = k0 + kk;
      int half = cp >> 7;
      int ci   = cp & 127;
      const float* Wsrc = (ci & 1) ? Wsg : Wm;
      Wt[cp*64 + (((kk>>3)^(cp&7))<<3) + (kk&7)] = f2bf(Wsrc[(size_t)(half*128 + k)*DOUTN + (ci>>1)]);
    }
    __syncthreads();
    #pragma unroll
    for(int g=0;g<8;g++){
      uint4 w0 = *(const uint4*)&Wt[ cx      *64 + ((g^(cx&7))<<3)];
      uint4 w1 = *(const uint4*)&Wt[(cx+128) *64 + ((g^(cx&7))<<3)];
      float w0f[8], w1f[8];
      unpack8(w0,w0f); unpack8(w1,w1f);
      #pragma unroll
      for(int j=0;j<8;j++){
        const float* xp = &Hs[ry*8+j][k0 + g*8];
        float xr[8];
        *(float4*)&xr[0] = *(const float4*)xp;
        *(float4*)&xr[4] = *(const float4*)(xp+4);
        #pragma unroll
        for(int m=0;m<8;m++){
          acc[j][0] += xr[m]*w0f[m];
          acc[j][1] += xr[m]*w1f[m];
        }
      }
    }
  }
  #pragma unroll
  for(int j=0;j<8;j++){
    size_t n = (size_t)(row0 + ry*8 + j);
    Bu[n*256 + cx]       = f2bf(acc[j][0]);   // SRC half
    Bu[n*256 + 128 + cx] = f2bf(acc[j][1]);   // DST half
  }
}

// ---------------- directed-edge heads (f32 out) ----------------
__global__ __launch_bounds__(256) void edge_kernel(const u16t* __restrict__ Bu,
                                                   const int*  __restrict__ ed,
                                                   const float* __restrict__ nin,
                                                   const float* __restrict__ nout,
                                                   float* __restrict__ ein,
                                                   float* __restrict__ eout){
  int e = blockIdx.x*4 + (threadIdx.x>>6);
  int l = threadIdx.x & 63;
  int s = ed[e], d = ed[EDIR+e];
  const u32t* rs = (const u32t*)(Bu + (size_t)s*256);
  const u32t* rd = (const u32t*)(Bu + (size_t)d*256);
  float2 Ss = up2(rs[l]);        // SRC[s]
  float2 Ds = up2(rs[64+l]);     // DST[s]
  float2 Sd = up2(rd[l]);        // SRC[d]
  float2 Dd = up2(rd[64+l]);     // DST[d]
  size_t o = (size_t)e*DOUTN + l;
  float miu_in  = Ss.x + Dd.x, ls_in  = Ss.y + Dd.y;
  float miu_out = Sd.x + Ds.x, ls_out = Sd.y + Ds.y;
  ein[o]  = nin[o]  * __expf(ls_in)  + miu_in;
  eout[o] = nout[o] * __expf(ls_out) + miu_out;
}

// ---------------- bi gather-reduce + finalize (fused, no atomics) ----------------
__global__ __launch_bounds__(256) void bi_gather_kernel(const u16t* __restrict__ Bu,
                                                        const uint2* __restrict__ bucket,
                                                        const u32t* __restrict__ offs,
                                                        const float* __restrict__ nn,
                                                        float* __restrict__ out){
  int n = blockIdx.x*4 + (threadIdx.x>>6);
  if(n >= NNODE) return;
  int l = threadIdx.x & 63;
  const u32t* Bw = (const u32t*)Bu;
  float2 S = up2(Bw[(size_t)n*128 + l]);           // SRC[n] (miu_l, sigma_l)
  u32t start = offs[n], end = offs[n+1];
  float nmiu = 0.f, nvar = 0.f;
  for(u32t b = start; b < end; b += 64){
    int nb = min(64, (int)(end - b));
    uint2 ent = make_uint2(0u, 0u);
    if(l < nb) ent = bucket[b + l];
    for(int j=0;j<nb;j++){
      u32t b1 = __shfl(ent.x, j);
      float v = __uint_as_float(__shfl((int)ent.y, j));
      float2 D = up2(Bw[(size_t)b1*128 + 64 + l]); // DST[b1]
      nmiu += v*(S.x + D.x);
      nvar += v*v*__expf(S.y + D.y);
    }
  }
  size_t o = (size_t)n*DOUTN + l;
  // exp(0.5*log(v)) == sqrt(v); v==0 -> 0 matches reference
  out[o] = nn[o]*sqrtf(nvar) + nmiu;
}

extern "C" void kernel_launch(void* const* d_in, const int* in_sizes, int n_in,
                              void* d_out, int out_size, void* d_ws, size_t ws_size,
                              hipStream_t stream){
  const float* X    = (const float*)d_in[0];
  const float* Wg   = (const float*)d_in[1];
  const float* Wm   = (const float*)d_in[2];
  const float* Wsg  = (const float*)d_in[3];
  const float* gv   = (const float*)d_in[4];
  const float* bv   = (const float*)d_in[5];
  const float* nin  = (const float*)d_in[6];
  const float* nout = (const float*)d_in[7];
  const float* nnod = (const float*)d_in[8];
  const int*  gi   = (const int*)d_in[9];
  const int*  ed   = (const int*)d_in[10];
  const int*  be   = (const int*)d_in[11];

  // workspace (76.8 MB):
  // region A [0, 51.2 MB):
  //   early:  gcn bucket uint2 @0 (12.8MB) | goffs @12.8M | gcur @13.2M+8 | gpart @13.7M (1572B)
  //           xwb bf16 @25.6M (25.6MB)
  //   late:   Bu (N x 512B) — overwrites all of A after gcn phase is dead
  // region B [51.2, 76.8 MB):
  //   early:  hidden bf16-packed u32 words (25.6MB)
  //   late:   bi bucket uint2 @51.2M (8MB) | boffs @59.2M | bcur @59.6M+8 | bpart @60.1M
  char* ws = (char*)d_ws;
  uint2* gbuck   = (uint2*)ws;
  u32t*  goffs   = (u32t*)(ws + 12800000);
  u32t*  gcur    = (u32t*)(ws + 13200008);
  u32t*  gpart   = (u32t*)(ws + 13700000);
  u16t*  xwb     = (u16t*)(ws + 25600000);
  u32t*  hiddenw = (u32t*)(ws + 51200000);
  u16t*  Bu      = (u16t*)ws;
  uint2* bbuck   = (uint2*)(ws + 51200000);
  u32t*  boffs   = (u32t*)(ws + 59200000);
  u32t*  bcur    = (u32t*)(ws + 59600008);
  u32t*  bpart   = (u32t*)(ws + 60100000);

  float* out  = (float*)d_out;
  float* ein  = out + (size_t)NNODE*DOUTN;
  float* eout = ein + (size_t)EDIR*DOUTN;

  // --- GCN aggregation via counting-sort + gather-reduce ---
  hipMemsetAsync(gcur, 0, NNODE*sizeof(u32t), stream);
  hist_kernel      <<<NNZE/256,    256,  0, stream>>>(gi, NNZE, gcur);
  scanA_kernel     <<<NBLKS,       256,  0, stream>>>(gcur, goffs, gpart);
  scanB_kernel     <<<1,           512,  0, stream>>>(gpart);
  scanC_kernel     <<<NBLKS,       256,  0, stream>>>(goffs, gcur, gpart);
  bucket_kernel    <<<NNZE/256,    256,  0, stream>>>(gi, gi+NNZE, gv, NNZE, gcur, gbuck);
  gemm1_kernel     <<<NNODE/16,    256,  0, stream>>>(X, Wg, xwb);
  gcn_gather_kernel<<<NNODE/4,     256,  0, stream>>>(xwb, gbuck, goffs, hiddenw);
  gemm2_kernel     <<<NNODE/16,    256,  0, stream>>>(hiddenw, Wm, Wsg, Bu);
  // --- BI bucketing (region B free now) ---
  hipMemsetAsync(bcur, 0, NNODE*sizeof(u32t), stream);
  hist_kernel      <<<(EBI+255)/256, 256,  0, stream>>>(be, EBI, bcur);
  scanA_kernel     <<<NBLKS,       256,  0, stream>>>(bcur, boffs, bpart);
  scanB_kernel     <<<1,           512,  0, stream>>>(bpart);
  scanC_kernel     <<<NBLKS,       256,  0, stream>>>(boffs, bcur, bpart);
  bucket_kernel    <<<(EBI+255)/256, 256,  0, stream>>>(be, be+EBI, bv, EBI, bcur, bbuck);
  // --- heads ---
  edge_kernel      <<<EDIR/4,      256,  0, stream>>>(Bu, ed, nin, nout, ein, eout);
  bi_gather_kernel <<<NNODE/4,     256,  0, stream>>>(Bu, bbuck, boffs, nnod, out);
}

// Round 7
// 709.285 us; speedup vs baseline: 3.2314x; 1.4014x over previous
//
#include <hip/hip_runtime.h>

typedef unsigned short u16t;
typedef unsigned int   u32t;

#define NNODE 100000
#define DIN   256
#define HIDN  128
#define DOUTN 64
#define NNZE  1600000
#define EDIR  500000
#define EBI   1000000
#define NBLKS 391            // ceil(NNODE/256)
#define G64   1563           // ceil(NNODE/64)

typedef __attribute__((ext_vector_type(8))) short bf16x8;
typedef __attribute__((ext_vector_type(4))) float f32x4;

__device__ __forceinline__ u16t f2bf(float f){
  u32t u = __float_as_uint(f);
  u += 0x7FFFu + ((u>>16)&1u);          // round-to-nearest-even
  return (u16t)(u>>16);
}
__device__ __forceinline__ float2 up2(u32t w){
  return make_float2(__uint_as_float(w<<16), __uint_as_float(w&0xFFFF0000u));
}

// ---------------- weight prep: fragment-ready bf16 layouts ----------------
// element (l,e) of frag f: k_in = (e>>2)*16 + (l>>4)*4 + (e&3)
// Wg_pre [ks8][nf8][l][e] from Wg[256][128]; Wc_pre [ks4][nf16][l][e] from Wm/Wsg packed cols
__global__ __launch_bounds__(256) void prep_kernel(const float* __restrict__ Wg,
                                                   const float* __restrict__ Wm,
                                                   const float* __restrict__ Wsg,
                                                   u16t* __restrict__ Wg_pre,
                                                   u16t* __restrict__ Wc_pre){
  int idx = blockIdx.x*256 + threadIdx.x;       // 0..65535
  int e = idx & 7, l = (idx>>3) & 63, f = (idx>>9) & 63, sel = idx>>15;
  int k_in = ((e>>2)<<4) + ((l>>4)<<2) + (e&3);
  if(sel == 0){
    int ks = f>>3, nf = f&7;
    int k = ks*32 + k_in, n = nf*16 + (l&15);
    Wg_pre[idx] = f2bf(Wg[(size_t)k*HIDN + n]);
  } else {
    int ks = f>>4, nf = f&15;
    int k = ks*32 + k_in, c = nf*16 + (l&15);
    int half = c>>7, ci = c&127;
    const float* src = (ci&1) ? Wsg : Wm;
    Wc_pre[idx - 32768] = f2bf(src[(size_t)(half*128 + k)*DOUTN + (ci>>1)]);
  }
}

// ---------------- histogram: cnt[key]++ ----------------
__global__ __launch_bounds__(256) void hist_kernel(const int* __restrict__ keys, int E,
                                                   u32t* __restrict__ cnt){
  int e = blockIdx.x*256 + threadIdx.x;
  if(e < E) atomicAdd(&cnt[keys[e]], 1u);
}

// ---------------- hierarchical scan ----------------
__global__ __launch_bounds__(256) void scanA_kernel(const u32t* __restrict__ cnt,
                                                    u32t* __restrict__ offs,
                                                    u32t* __restrict__ partials){
  __shared__ u32t sh[256];
  int t = threadIdx.x, idx = blockIdx.x*256 + t;
  u32t v = (idx < NNODE) ? cnt[idx] : 0u;
  sh[t] = v; __syncthreads();
  #pragma unroll
  for(int off=1; off<256; off<<=1){
    u32t x = (t>=off) ? sh[t-off] : 0u;
    __syncthreads();
    sh[t] += x;
    __syncthreads();
  }
  if(idx < NNODE) offs[idx] = sh[t] - v;
  if(t == 255) partials[blockIdx.x] = sh[255];
}
__global__ __launch_bounds__(512) void scanB_kernel(u32t* __restrict__ partials){
  __shared__ u32t sh[512];
  int t = threadIdx.x;
  u32t v = (t < NBLKS) ? partials[t] : 0u;
  sh[t] = v; __syncthreads();
  #pragma unroll
  for(int off=1; off<512; off<<=1){
    u32t x = (t>=off) ? sh[t-off] : 0u;
    __syncthreads();
    sh[t] += x;
    __syncthreads();
  }
  if(t < NBLKS) partials[t] = sh[t] - v;
  if(t == 511) partials[NBLKS] = sh[511];
}
__global__ __launch_bounds__(256) void scanC_kernel(u32t* __restrict__ offs,
                                                    u32t* __restrict__ cur,
                                                    const u32t* __restrict__ partials){
  int idx = blockIdx.x*256 + threadIdx.x;
  if(idx < NNODE){
    u32t o = offs[idx] + partials[blockIdx.x];
    offs[idx] = o; cur[idx] = o;
  }
  if(idx == 0) offs[NNODE] = partials[NBLKS];
}

// ---------------- bucket fill ----------------
__global__ __launch_bounds__(256) void bucket_kernel(const int* __restrict__ keys,
                                                     const int* __restrict__ pay,
                                                     const float* __restrict__ val,
                                                     int E,
                                                     u32t* __restrict__ cur,
                                                     uint2* __restrict__ bucket){
  int e = blockIdx.x*256 + threadIdx.x;
  if(e < E){
    u32t pos = atomicAdd(&cur[keys[e]], 1u);
    bucket[pos] = make_uint2((u32t)pay[e], __float_as_uint(val[e]));
  }
}

// ---------------- GEMM1 (MFMA): xw[N][128] = X[N][256] @ Wg, bf16 out ----------------
// block = 4 waves x 16 rows = 64 rows; B-frags read from L2-resident Wg_pre
__global__ __launch_bounds__(256) void gemm1_kernel(const float* __restrict__ X,
                                                    const u16t* __restrict__ Wg_pre,
                                                    u16t* __restrict__ xwb){
  __shared__ __align__(16) u16t Xs[64*256];   // 32 KB, 8B-granule XOR-swizzled
  const int t = threadIdx.x, l = t & 63, w = t >> 6;
  const int row0 = blockIdx.x * 64;
  for(int i=0;i<16;i++){
    int m = w*16 + i;
    int mg = min(row0 + m, NNODE-1);
    float4 f = *(const float4*)&X[(size_t)mg*DIN + l*4];
    u32t lo = (u32t)f2bf(f.x) | ((u32t)f2bf(f.y)<<16);
    u32t hi = (u32t)f2bf(f.z) | ((u32t)f2bf(f.w)<<16);
    u32t* p = (u32t*)&Xs[m*256 + ((l ^ (m&15))<<2)];
    p[0] = lo; p[1] = hi;
  }
  __syncthreads();
  f32x4 acc[8];
  #pragma unroll
  for(int nf=0;nf<8;nf++) acc[nf] = (f32x4)(0.f);
  const int lm = l & 15, l4 = l >> 4;
  const int mrow = w*16 + lm;
  #pragma unroll 1
  for(int ks=0; ks<8; ks++){
    int kg = ks*8 + l4;
    union { uint2 u2[2]; bf16x8 v; } a;
    a.u2[0] = *(const uint2*)&Xs[mrow*256 + ((kg     ^ lm)<<2)];
    a.u2[1] = *(const uint2*)&Xs[mrow*256 + (((kg+4) ^ lm)<<2)];
    #pragma unroll
    for(int nf=0;nf<8;nf++){
      union { uint4 u4; bf16x8 v; } b;
      b.u4 = *(const uint4*)&Wg_pre[(size_t)((ks*8+nf)*64 + l)*8];
      acc[nf] = __builtin_amdgcn_mfma_f32_16x16x32_bf16(a.v, b.v, acc[nf], 0, 0, 0);
    }
  }
  #pragma unroll
  for(int r=0;r<4;r++){
    int gr = row0 + w*16 + l4*4 + r;
    if(gr < NNODE){
      #pragma unroll
      for(int nf=0;nf<8;nf++)
        xwb[(size_t)gr*HIDN + nf*16 + lm] = f2bf(acc[nf][r]);
    }
  }
}

// ---------------- GCN gather-reduce ----------------
__global__ __launch_bounds__(256) void gcn_gather_kernel(const u16t* __restrict__ xwb,
                                                         const uint2* __restrict__ bucket,
                                                         const u32t* __restrict__ offs,
                                                         u32t* __restrict__ hiddenw){
  int n = blockIdx.x*4 + (threadIdx.x>>6);
  if(n >= NNODE) return;
  int l = threadIdx.x & 63;
  u32t start = offs[n], end = offs[n+1];
  const u32t* xww = (const u32t*)xwb;
  float acc0 = 0.f, acc1 = 0.f;
  for(u32t b = start; b < end; b += 64){
    int nb = min(64, (int)(end - b));
    uint2 ent = make_uint2(0u, 0u);
    if(l < nb) ent = bucket[b + l];
    for(int j=0;j<nb;j++){
      u32t s  = __shfl(ent.x, j);
      float v = __uint_as_float(__shfl((int)ent.y, j));
      float2 x = up2(xww[(size_t)s*64 + l]);
      acc0 += v*x.x;
      acc1 += v*x.y;
    }
  }
  hiddenw[(size_t)n*64 + l] = (u32t)f2bf(acc0) | ((u32t)f2bf(acc1)<<16);
}

// ---------------- GEMM2 (MFMA): Bu[N][256] = hidden[N][128] @ Wcat ----------------
__global__ __launch_bounds__(256) void gemm2_kernel(const u32t* __restrict__ hiddenw,
                                                    const u16t* __restrict__ Wc_pre,
                                                    u16t* __restrict__ Bu){
  __shared__ __align__(16) u16t Hs[64*128];   // 16 KB
  const int t = threadIdx.x, l = t & 63, w = t >> 6;
  const int row0 = blockIdx.x * 64;
  for(int i=0;i<16;i++){
    int m = w*16 + i;
    int mg = min(row0 + m, NNODE-1);
    u32t v = hiddenw[(size_t)mg*64 + l];
    *(u32t*)&Hs[m*128 + (((l>>1) ^ (m&15))<<2) + ((l&1)<<1)] = v;
  }
  __syncthreads();
  f32x4 acc[16];
  #pragma unroll
  for(int nf=0;nf<16;nf++) acc[nf] = (f32x4)(0.f);
  const int lm = l & 15, l4 = l >> 4;
  const int mrow = w*16 + lm;
  #pragma unroll 1
  for(int ks=0; ks<4; ks++){
    int kg = ks*8 + l4;
    union { uint2 u2[2]; bf16x8 v; } a;
    a.u2[0] = *(const uint2*)&Hs[mrow*128 + ((kg     ^ lm)<<2)];
    a.u2[1] = *(const uint2*)&Hs[mrow*128 + (((kg+4) ^ lm)<<2)];
    #pragma unroll
    for(int nf=0;nf<16;nf++){
      union { uint4 u4; bf16x8 v; } b;
      b.u4 = *(const uint4*)&Wc_pre[(size_t)((ks*16+nf)*64 + l)*8];
      acc[nf] = __builtin_amdgcn_mfma_f32_16x16x32_bf16(a.v, b.v, acc[nf], 0, 0, 0);
    }
  }
  #pragma unroll
  for(int r=0;r<4;r++){
    int gr = row0 + w*16 + l4*4 + r;
    if(gr < NNODE){
      #pragma unroll
      for(int nf=0;nf<16;nf++)
        Bu[(size_t)gr*256 + nf*16 + lm] = f2bf(acc[nf][r]);
    }
  }
}

// ---------------- directed-edge heads (f32 out) ----------------
__global__ __launch_bounds__(256) void edge_kernel(const u16t* __restrict__ Bu,
                                                   const int*  __restrict__ ed,
                                                   const float* __restrict__ nin,
                                                   const float* __restrict__ nout,
                                                   float* __restrict__ ein,
                                                   float* __restrict__ eout){
  int e = blockIdx.x*4 + (threadIdx.x>>6);
  int l = threadIdx.x & 63;
  int s = ed[e], d = ed[EDIR+e];
  const u32t* rs = (const u32t*)(Bu + (size_t)s*256);
  const u32t* rd = (const u32t*)(Bu + (size_t)d*256);
  float2 Ss = up2(rs[l]);
  float2 Ds = up2(rs[64+l]);
  float2 Sd = up2(rd[l]);
  float2 Dd = up2(rd[64+l]);
  size_t o = (size_t)e*DOUTN + l;
  float miu_in  = Ss.x + Dd.x, ls_in  = Ss.y + Dd.y;
  float miu_out = Sd.x + Ds.x, ls_out = Sd.y + Ds.y;
  ein[o]  = nin[o]  * __expf(ls_in)  + miu_in;
  eout[o] = nout[o] * __expf(ls_out) + miu_out;
}

// ---------------- bi gather-reduce + finalize ----------------
__global__ __launch_bounds__(256) void bi_gather_kernel(const u16t* __restrict__ Bu,
                                                        const uint2* __restrict__ bucket,
                                                        const u32t* __restrict__ offs,
                                                        const float* __restrict__ nn,
                                                        float* __restrict__ out){
  int n = blockIdx.x*4 + (threadIdx.x>>6);
  if(n >= NNODE) return;
  int l = threadIdx.x & 63;
  const u32t* Bw = (const u32t*)Bu;
  float2 S = up2(Bw[(size_t)n*128 + l]);
  u32t start = offs[n], end = offs[n+1];
  float nmiu = 0.f, nvar = 0.f;
  for(u32t b = start; b < end; b += 64){
    int nb = min(64, (int)(end - b));
    uint2 ent = make_uint2(0u, 0u);
    if(l < nb) ent = bucket[b + l];
    for(int j=0;j<nb;j++){
      u32t b1 = __shfl(ent.x, j);
      float v = __uint_as_float(__shfl((int)ent.y, j));
      float2 D = up2(Bw[(size_t)b1*128 + 64 + l]);
      nmiu += v*(S.x + D.x);
      nvar += v*v*__expf(S.y + D.y);
    }
  }
  size_t o = (size_t)n*DOUTN + l;
  out[o] = nn[o]*sqrtf(nvar) + nmiu;
}

extern "C" void kernel_launch(void* const* d_in, const int* in_sizes, int n_in,
                              void* d_out, int out_size, void* d_ws, size_t ws_size,
                              hipStream_t stream){
  const float* X    = (const float*)d_in[0];
  const float* Wg   = (const float*)d_in[1];
  const float* Wm   = (const float*)d_in[2];
  const float* Wsg  = (const float*)d_in[3];
  const float* gv   = (const float*)d_in[4];
  const float* bv   = (const float*)d_in[5];
  const float* nin  = (const float*)d_in[6];
  const float* nout = (const float*)d_in[7];
  const float* nnod = (const float*)d_in[8];
  const int*  gi   = (const int*)d_in[9];
  const int*  ed   = (const int*)d_in[10];
  const int*  be   = (const int*)d_in[11];

  // workspace (76.8 MB):
  // region A [0, 51.2 MB):
  //   early:  gcn bucket uint2 @0 (12.8MB) | goffs @12.8M | gcur @13.2M+8 | gpart @13.7M
  //           xwb bf16 @25.6M (25.6MB)
  //   late:   Bu (N x 512B) — overwrites all of A after gcn phase is dead
  // region B [51.2, 76.8 MB):
  //   early:  hidden bf16-packed u32 words (25.6MB)
  //   late:   bi bucket uint2 @51.2M (8MB) | boffs @59.2M | bcur @59.6M+8 | bpart @60.1M
  char* ws = (char*)d_ws;
  uint2* gbuck   = (uint2*)ws;
  u32t*  goffs   = (u32t*)(ws + 12800000);
  u32t*  gcur    = (u32t*)(ws + 13200008);
  u32t*  gpart   = (u32t*)(ws + 13700000);
  u16t*  xwb     = (u16t*)(ws + 25600000);
  u32t*  hiddenw = (u32t*)(ws + 51200000);
  u16t*  Bu      = (u16t*)ws;
  uint2* bbuck   = (uint2*)(ws + 51200000);
  u32t*  boffs   = (u32t*)(ws + 59200000);
  u32t*  bcur    = (u32t*)(ws + 59600008);
  u32t*  bpart   = (u32t*)(ws + 60100000);

  float* out  = (float*)d_out;
  float* ein  = out + (size_t)NNODE*DOUTN;
  float* eout = ein + (size_t)EDIR*DOUTN;
  // weight-prep arrays live in the tail of d_out's node region (bytes [25.47M, 25.6M));
  // dead by the time bi_gather overwrites the node region at the end of the launch.
  u16t* Wg_pre = (u16t*)((char*)d_out + 25600000 - 131072);
  u16t* Wc_pre = Wg_pre + 32768;

  prep_kernel      <<<256,         256,  0, stream>>>(Wg, Wm, Wsg, Wg_pre, Wc_pre);
  // --- GCN aggregation via counting-sort + gather-reduce ---
  hipMemsetAsync(gcur, 0, NNODE*sizeof(u32t), stream);
  hist_kernel      <<<NNZE/256,    256,  0, stream>>>(gi, NNZE, gcur);
  scanA_kernel     <<<NBLKS,       256,  0, stream>>>(gcur, goffs, gpart);
  scanB_kernel     <<<1,           512,  0, stream>>>(gpart);
  scanC_kernel     <<<NBLKS,       256,  0, stream>>>(goffs, gcur, gpart);
  bucket_kernel    <<<NNZE/256,    256,  0, stream>>>(gi, gi+NNZE, gv, NNZE, gcur, gbuck);
  gemm1_kernel     <<<G64,         256,  0, stream>>>(X, Wg_pre, xwb);
  gcn_gather_kernel<<<NNODE/4,     256,  0, stream>>>(xwb, gbuck, goffs, hiddenw);
  gemm2_kernel     <<<G64,         256,  0, stream>>>(hiddenw, Wc_pre, Bu);
  // --- BI bucketing (region B free now) ---
  hipMemsetAsync(bcur, 0, NNODE*sizeof(u32t), stream);
  hist_kernel      <<<(EBI+255)/256, 256,  0, stream>>>(be, EBI, bcur);
  scanA_kernel     <<<NBLKS,       256,  0, stream>>>(bcur, boffs, bpart);
  scanB_kernel     <<<1,           512,  0, stream>>>(bpart);
  scanC_kernel     <<<NBLKS,       256,  0, stream>>>(boffs, bcur, bpart);
  bucket_kernel    <<<(EBI+255)/256, 256,  0, stream>>>(be, be+EBI, bv, EBI, bcur, bbuck);
  // --- heads ---
  edge_kernel      <<<EDIR/4,      256,  0, stream>>>(Bu, ed, nin, nout, ein, eout);
  bi_gather_kernel <<<NNODE/4,     256,  0, stream>>>(Bu, bbuck, boffs, nnod, out);
}